// Round 3
// baseline (352.382 us; speedup 1.0000x reference)
//
#include <hip/hip_runtime.h>
#include <stdint.h>

typedef unsigned short u16;
typedef __attribute__((ext_vector_type(8))) short short8;
typedef __attribute__((ext_vector_type(4))) short s16x4;
typedef __attribute__((ext_vector_type(4))) float f32x4;
typedef __attribute__((ext_vector_type(4))) unsigned short u16x4;

#define S_LEN 2048
#define NH 16
#define DMODEL 1024
#define NR 129
#define LOG2E 1.44269504f

#define MFMA(a,b,c) __builtin_amdgcn_mfma_f32_16x16x32_bf16((a),(b),(c),0,0,0)

__device__ __forceinline__ u16 f2bf(float f){            // RTNE (for Q/K/V/emb)
  uint32_t u = __float_as_uint(f);
  u += 0x7fff + ((u >> 16) & 1);
  return (u16)(u >> 16);
}
__device__ __forceinline__ u16 f2bfa(float f){           // RTNA (cheap, for p>=0)
  return (u16)((__float_as_uint(f) + 0x8000u) >> 16);
}
__device__ __forceinline__ float bf2f(u16 h){ return __uint_as_float(((uint32_t)h) << 16); }

// packed f32x2 -> bf16x2 (RTNE), single VALU op
__device__ __forceinline__ uint32_t cvtpk(float lo, float hi){
  uint32_t r;
  asm("v_cvt_pk_bf16_f32 %0, %1, %2" : "=v"(r) : "v"(lo), "v"(hi));
  return r;
}

// async global->LDS, 16B per lane; lds dest must be wave-uniform base (+lane*16 by HW)
__device__ __forceinline__ void gl_lds16(const u16* g, u16* l){
  __builtin_amdgcn_global_load_lds((const __attribute__((address_space(1))) void*)g,
                                   (__attribute__((address_space(3))) void*)l, 16, 0, 0);
}

// ---------------- prep: convx + transw + convemb + mask*log2e, one launch ----------------
// blocks: [0,4096) convx | [4096,4864) transw | [4864,4900) convemb | [4900,4916) maskL
__global__ __launch_bounds__(256) void k_prep(const float* __restrict__ X,
                                              const float* __restrict__ Wq, const float* __restrict__ Wk,
                                              const float* __restrict__ Wv, const float* __restrict__ Wemb,
                                              const float* __restrict__ mask,
                                              u16* __restrict__ Xb, u16* __restrict__ Wt,
                                              u16* __restrict__ Eb, float* __restrict__ maskL){
  const int bid = blockIdx.x, tid = threadIdx.x;
  if (bid < 4096){
    int i = bid * 256 + tid;
    const float4* xp = (const float4*)X;
    float4 v = xp[i];
    u16x4 o; o.x = f2bf(v.x); o.y = f2bf(v.y); o.z = f2bf(v.z); o.w = f2bf(v.w);
    *(u16x4*)(Xb + (size_t)i * 4) = o;
  } else if (bid < 4864){
    int b2 = bid - 4096;
    int z = b2 >> 8;
    const float* W = (z == 0) ? Wq : (z == 1) ? Wk : Wv;
    u16* Ot = Wt + (size_t)z * 1024 * 1024;
    __shared__ float t[64][65];
    int k0 = ((b2 >> 4) & 15) * 64, n0 = (b2 & 15) * 64;
    int c = tid & 63, r0 = (tid >> 6) * 16;
    #pragma unroll
    for (int i = 0; i < 16; ++i) t[r0 + i][c] = W[(size_t)(k0 + r0 + i) * 1024 + n0 + c];
    __syncthreads();
    #pragma unroll
    for (int i = 0; i < 16; ++i) Ot[(size_t)(n0 + r0 + i) * 1024 + k0 + c] = f2bf(t[c][r0 + i]);
  } else if (bid < 4900){
    int idx = (bid - 4864) * 256 + tid;
    if (idx < 144 * 64){
      int r = idx >> 6;
      Eb[idx] = (r < NR) ? f2bf(Wemb[idx]) : (u16)0;
    }
  } else {
    int idx = (bid - 4900) * 256 + tid;   // 4096 mask elements
    maskL[idx] = mask[idx] * LOG2E;
  }
}

// ---------------- QKV GEMM: [4096,1024] x Wt[1024,1024]^T, bf16 MFMA, m97 structure ----------------
// global_load_lds width-16 into LINEAR [128][32] tiles (conflict-free frag reads).
// z==0/1: out [g = b*16+h][s][j] bf16 (Q pre-scaled by 0.125*log2e).
// z==2:   V written DIRECTLY TRANSPOSED to Vt[g][d][s] (k_transv fused away).
__global__ __launch_bounds__(256) void k_qkv(const u16* __restrict__ Xb, const u16* __restrict__ Wt,
                                             const float* __restrict__ bq, const float* __restrict__ bk,
                                             const float* __restrict__ bv,
                                             u16* __restrict__ Qs, u16* __restrict__ Kb, u16* __restrict__ Vt){
  const int z = blockIdx.z;
  const u16* W = Wt + (size_t)z * 1024 * 1024;
  const float* bias = (z == 0) ? bq : (z == 1) ? bk : bv;
  const float vs = (z == 0) ? 0.125f * LOG2E : 1.0f;
  const int n0 = blockIdx.x * 128, m0 = blockIdx.y * 128;
  const int tid = threadIdx.x, w = tid >> 6, lane = tid & 63, l15 = lane & 15, quad = lane >> 4;
  const int wm = (w >> 1) * 64, wn = (w & 1) * 64;
  __shared__ __attribute__((aligned(16))) u16 As[128 * 32];
  __shared__ __attribute__((aligned(16))) u16 Bs[128 * 32];
  f32x4 acc[4][4];
  #pragma unroll
  for (int i = 0; i < 4; ++i)
    #pragma unroll
    for (int j = 0; j < 4; ++j) acc[i][j] = (f32x4){0.f,0.f,0.f,0.f};

  const int rA = lane >> 2, cA = (lane & 3) * 8;
  const u16* aBase = Xb + (size_t)(m0 + w * 16 + rA) * 1024 + cA;
  const u16* bBase = W  + (size_t)(n0 + w * 16 + rA) * 1024 + cA;
  u16* aDst0 = As + (w * 16) * 32;  u16* aDst1 = As + (64 + w * 16) * 32;
  u16* bDst0 = Bs + (w * 16) * 32;  u16* bDst1 = Bs + (64 + w * 16) * 32;

  for (int k0 = 0; k0 < 1024; k0 += 32){
    __syncthreads();
    gl_lds16(aBase + k0,             aDst0);
    gl_lds16(aBase + 64 * 1024 + k0, aDst1);
    gl_lds16(bBase + k0,             bDst0);
    gl_lds16(bBase + 64 * 1024 + k0, bDst1);
    __syncthreads();
    short8 af[4], bfr[4];
    #pragma unroll
    for (int f = 0; f < 4; ++f){
      af[f]  = *(const short8*)(As + (wm + f * 16 + l15) * 32 + quad * 8);
      bfr[f] = *(const short8*)(Bs + (wn + f * 16 + l15) * 32 + quad * 8);
    }
    #pragma unroll
    for (int i = 0; i < 4; ++i)
      #pragma unroll
      for (int j = 0; j < 4; ++j) acc[i][j] = MFMA(af[i], bfr[j], acc[i][j]);
  }

  if (z == 2){
    // transposed store: Vt[g][d][s], 4 consecutive s per lane -> u16x4 (8B)
    #pragma unroll
    for (int i = 0; i < 4; ++i){
      int row0 = m0 + wm + i * 16 + quad * 4;
      int bb = row0 >> 11, sb = row0 & 2047;
      #pragma unroll
      for (int j = 0; j < 4; ++j){
        int col = n0 + wn + j * 16 + l15;
        float bsv = bias[col];
        int hh = col >> 6, jd = col & 63;
        u16x4 vv;
        #pragma unroll
        for (int r = 0; r < 4; ++r) vv[r] = f2bf(acc[i][j][r] + bsv);
        *(u16x4*)(Vt + ((size_t)(bb * 16 + hh) * 64 + jd) * S_LEN + sb) = vv;
      }
    }
  } else {
    u16* outp = (z == 0) ? Qs : Kb;
    #pragma unroll
    for (int i = 0; i < 4; ++i){
      #pragma unroll
      for (int j = 0; j < 4; ++j){
        int col = n0 + wn + j * 16 + l15;
        float bsv = bias[col];
        int hh = col >> 6, jd = col & 63;
        #pragma unroll
        for (int r = 0; r < 4; ++r){
          int row = m0 + wm + i * 16 + quad * 4 + r;
          int bb = row >> 11, s = row & 2047;
          float vv = (acc[i][j][r] + bsv) * vs;
          outp[(((size_t)(bb * 16 + hh)) * S_LEN + s) * 64 + jd] = f2bf(vv);
        }
      }
    }
  }
}

// ---------------- fused flash + rel_v band, base-2 softmax, fixed m=0 ----------------
// This round:
//  - K fragments DIRECT from global (coalesced dwordx4, prefetched 1 tile ahead);
//    Ks LDS buffer deleted -> QK^T has zero LDS dependency.
//  - Vs: linear [2][64][64] double-buffer with 16B-granule XOR swizzle
//    (byte ^= (row&7)<<4): bank-uniform writes AND reads.
//  - ONE barrier per tile (write V(t+1) to buf^1 while reading buf).
__global__ __launch_bounds__(256, 3) void k_flash(const u16* __restrict__ QS, const u16* __restrict__ KB,
                                                  const u16* __restrict__ VT, const u16* __restrict__ EMBK,
                                                  const float* __restrict__ maskL, const float* __restrict__ embv,
                                                  float* __restrict__ out){
  const int g = blockIdx.y; const int b = g >> 4; const int h = g & 15;
  const int q0 = blockIdx.x * 64;
  const int tid = threadIdx.x;
  const int w = tid >> 6; const int lane = tid & 63;
  const int l15 = lane & 15; const int quad = lane >> 4;
  const int wm = w * 16;
  const int rqb = quad * 4;
  const int qrow = q0 + wm + l15;      // this lane's q-row (swapped layout)

  __shared__ union UKE {
    struct {
      __attribute__((aligned(16))) u16 Vs[2][64][64];   // 16,384  swizzled dbuf
      __attribute__((aligned(16))) u16 QEb[4][16][132]; // 16,896
    } s;
    __attribute__((aligned(16))) u16 Evs[64][136];      // 17,408 (tail only)
  } uu;                                                 // union = 33,280
  __shared__ __attribute__((aligned(16))) u16 Psb[64][136];  // 17,408 (total 50,688 -> 3 blk/CU)

  // zero Psb
  {
    short8 z8 = (short8){0,0,0,0,0,0,0,0};
    for (int i = tid; i < 64 * 136 / 8; i += 256) ((short8*)Psb)[i] = z8;
  }

  // V staging thread coords + swizzled dest byte offsets
  const int srow0 = tid >> 3;
  const int srow1 = srow0 + 32;
  const int sch = (tid & 7) * 8;
  const int c0b = (((sch & 8) ? 32 : 0) + (sch >> 4) * 4) * 2;   // byte offset (lo half)
  const int off00 = srow0 * 128 + ((c0b)      ^ ((srow0 & 7) << 4));
  const int off01 = srow0 * 128 + ((c0b + 32) ^ ((srow0 & 7) << 4));
  const int off10 = srow1 * 128 + ((c0b)      ^ ((srow1 & 7) << 4));
  const int off11 = srow1 * 128 + ((c0b + 32) ^ ((srow1 & 7) << 4));
  const u16* vSrc = VT + (size_t)g * 64 * S_LEN + sch;    // + row*S_LEN + kt
  const float* mBase = maskL + b * S_LEN;

  // K fragment base (per lane) + prologue loads for tile 0
  const u16* kfp = KB + ((size_t)g * S_LEN + l15) * 64 + quad * 8;
  short8 kf[4][2];
  #pragma unroll
  for (int fn = 0; fn < 4; ++fn){
    kf[fn][0] = *(const short8*)(kfp + (size_t)(fn * 16) * 64);
    kf[fn][1] = *(const short8*)(kfp + (size_t)(fn * 16) * 64 + 32);
  }

  // V prologue: V(0) -> Vs[0]; then vr <- V(64)
  short8 vr0 = *(const short8*)(vSrc + (size_t)srow0 * S_LEN);
  short8 vr1 = *(const short8*)(vSrc + (size_t)srow1 * S_LEN);
  {
    char* vb = (char*)uu.s.Vs[0];
    *(s16x4*)(vb + off00) = __builtin_shufflevector(vr0, vr0, 0, 1, 2, 3);
    *(s16x4*)(vb + off01) = __builtin_shufflevector(vr0, vr0, 4, 5, 6, 7);
    *(s16x4*)(vb + off10) = __builtin_shufflevector(vr1, vr1, 0, 1, 2, 3);
    *(s16x4*)(vb + off11) = __builtin_shufflevector(vr1, vr1, 4, 5, 6, 7);
  }
  vr0 = *(const short8*)(vSrc + (size_t)srow0 * S_LEN + 64);
  vr1 = *(const short8*)(vSrc + (size_t)srow1 * S_LEN + 64);

  f32x4 mcur[4];
  #pragma unroll
  for (int fn = 0; fn < 4; ++fn) mcur[fn] = *(const f32x4*)(mBase + fn * 16 + rqb);

  // Q fragments straight from global
  const u16* qptr = QS + ((size_t)g * S_LEN + q0 + wm + l15) * 64 + quad * 8;
  short8 qa0 = *(const short8*)qptr;
  short8 qa1 = *(const short8*)(qptr + 32);

  // qe = Q @ emb_k^T (this wave's 16 rows; cols 0..128), bf16 into wave-private LDS
  #pragma unroll
  for (int fn = 0; fn < 9; ++fn){
    const u16* ep = EMBK + (fn * 16 + l15) * 64 + quad * 8;
    short8 eb0 = *(const short8*)ep;
    short8 eb1 = *(const short8*)(ep + 32);
    f32x4 c = (f32x4){0.f,0.f,0.f,0.f};
    c = MFMA(qa0, eb0, c);
    c = MFMA(qa1, eb1, c);
    int col = fn * 16 + l15;
    if (col < NR){
      #pragma unroll
      for (int r = 0; r < 4; ++r) uu.s.QEb[w][rqb + r][col] = f2bf(c[r]);
    }
  }
  __syncthreads();   // QEb + Psb-zero + Vs[0] visible

  const float qeR = bf2f(uu.s.QEb[w][l15][0]);     // lane-constant (row = l15)
  const float qeL = bf2f(uu.s.QEb[w][l15][128]);

  // ones-column B fragment for MFMA row-sums
  short8 bones;
  {
    short one = (l15 == 0) ? (short)0x3F80 : (short)0;
    #pragma unroll
    for (int j = 0; j < 8; ++j) bones[j] = one;
  }

  // swizzled V read offsets
  const int vswz = (l15 & 7) << 4;
  const int vrb  = l15 * 128;                 // + fd*2048 per fragment row-group
  const int vq0  = (quad * 32) ^ vswz;        // fp = 0
  const int vq1  = (quad * 32 + 16) ^ vswz;   // fp = 1

  f32x4 o[4];
  #pragma unroll
  for (int f = 0; f < 4; ++f) o[f] = (f32x4){0.f,0.f,0.f,0.f};
  f32x4 lacc = (f32x4){0.f,0.f,0.f,0.f};
  float ll0v[4] = {0.f,0.f,0.f,0.f};
  float ll_mx = 0.f;
  float rsb_s = 0.f;

  int cur = 0;
  for (int kt = 0; kt < S_LEN; kt += 64){
    const int ktn = kt + 64;

    // stage V(kt+64) -> Vs[cur^1] (race-free: that buffer's readers finished
    // before the barrier that ended the previous iteration)
    {
      char* vb = (char*)uu.s.Vs[cur ^ 1];
      *(s16x4*)(vb + off00) = __builtin_shufflevector(vr0, vr0, 0, 1, 2, 3);
      *(s16x4*)(vb + off01) = __builtin_shufflevector(vr0, vr0, 4, 5, 6, 7);
      *(s16x4*)(vb + off10) = __builtin_shufflevector(vr1, vr1, 0, 1, 2, 3);
      *(s16x4*)(vb + off11) = __builtin_shufflevector(vr1, vr1, 4, 5, 6, 7);
    }

    const bool leftC  = (kt <= q0 - 128);
    const bool rightC = (kt >= q0 + 128);
    const float qeadd = leftC ? qeL : (rightC ? qeR : 0.f);

    // QK^T from registers (zero LDS dependency); C-init = mask(+qe)
    f32x4 p4[4];
    __builtin_amdgcn_s_setprio(1);
    #pragma unroll
    for (int fn = 0; fn < 4; ++fn){
      f32x4 c = mcur[fn] + qeadd;
      c = MFMA(kf[fn][0], qa0, c);
      c = MFMA(kf[fn][1], qa1, c);
      p4[fn] = c;
    }
    __builtin_amdgcn_s_setprio(0);

    // prefetch next K frags / mask / V regs (overlap exp + PV + barrier)
    f32x4 mnext[4];
    if (ktn < S_LEN){
      #pragma unroll
      for (int fn = 0; fn < 4; ++fn){
        kf[fn][0] = *(const short8*)(kfp + (size_t)(ktn + fn * 16) * 64);
        kf[fn][1] = *(const short8*)(kfp + (size_t)(ktn + fn * 16) * 64 + 32);
      }
      #pragma unroll
      for (int fn = 0; fn < 4; ++fn) mnext[fn] = *(const f32x4*)(mBase + ktn + fn * 16 + rqb);
      if (kt + 128 < S_LEN){
        vr0 = *(const short8*)(vSrc + (size_t)srow0 * S_LEN + kt + 128);
        vr1 = *(const short8*)(vSrc + (size_t)srow1 * S_LEN + kt + 128);
      }
    }

    if (leftC | rightC){
      #pragma unroll
      for (int fn = 0; fn < 4; ++fn)
        #pragma unroll
        for (int r = 0; r < 4; ++r) p4[fn][r] = __builtin_amdgcn_exp2f(p4[fn][r]);
    } else {
      // mixed: per-element qe gather + band capture
      #pragma unroll
      for (int fn = 0; fn < 4; ++fn){
        int kbase = kt + fn * 16 + rqb;
        #pragma unroll
        for (int r = 0; r < 4; ++r){
          int dq = qrow - (kbase + r) + 64;     // unclamped rel idx
          int ridx = min(max(dq, 0), 128);
          float p = __builtin_amdgcn_exp2f(p4[fn][r] + bf2f(uu.s.QEb[w][l15][ridx]));
          ll_mx += (dq >= 128) ? p : 0.f;
          if (dq >= 1 && dq <= 127){            // band element: t = 127 - dq
            Psb[wm + l15][127 - dq] = f2bfa(p);
            rsb_s += p;
          }
          p4[fn][r] = p;
        }
      }
    }

    // pack P (cvt_pk), MFMA row-sum, PV from Vs[cur]
    __builtin_amdgcn_s_setprio(1);
    const char* vbase = (const char*)uu.s.Vs[cur];
    #pragma unroll
    for (int fp = 0; fp < 2; ++fp){
      union { uint32_t u[4]; short8 s8; } pk;
      pk.u[0] = cvtpk(p4[2 * fp][0],     p4[2 * fp][1]);
      pk.u[1] = cvtpk(p4[2 * fp][2],     p4[2 * fp][3]);
      pk.u[2] = cvtpk(p4[2 * fp + 1][0], p4[2 * fp + 1][1]);
      pk.u[3] = cvtpk(p4[2 * fp + 1][2], p4[2 * fp + 1][3]);
      short8 pa = pk.s8;
      lacc = MFMA(pa, bones, lacc);
      const int vq = fp ? vq1 : vq0;
      #pragma unroll
      for (int fd = 0; fd < 4; ++fd){
        short8 vb = *(const short8*)(vbase + fd * 2048 + vrb + vq);
        o[fd] = MFMA(pa, vb, o[fd]);
      }
    }
    __builtin_amdgcn_s_setprio(0);

    if (kt == q0 - 128){
      #pragma unroll
      for (int r = 0; r < 4; ++r) ll0v[r] = lacc[r];
    }
    if (ktn < S_LEN){
      #pragma unroll
      for (int fn = 0; fn < 4; ++fn) mcur[fn] = mnext[fn];
    }
    __syncthreads();   // single barrier per tile
    cur ^= 1;
  }

  // ---- band tail ----
  // build Evs in the union region: Evs[d][t] = emb_v[127-t][d] (t<=126), else 0
  {
    int d = tid & 63, t4 = tid >> 6;
    #pragma unroll
    for (int it = 0; it < 34; ++it){
      int t = t4 + it * 4;
      float v = (t <= 126) ? embv[(size_t)(127 - t) * 64 + d] : 0.f;
      uu.Evs[d][t] = f2bf(v);
    }
  }
  __syncthreads();

  f32x4 ob[4];
  #pragma unroll
  for (int f = 0; f < 4; ++f) ob[f] = (f32x4){0.f,0.f,0.f,0.f};
  #pragma unroll
  for (int kb = 0; kb < 4; ++kb){
    short8 pa = *(const short8*)&Psb[wm + l15][kb * 32 + quad * 8];
    #pragma unroll
    for (int fd = 0; fd < 4; ++fd){
      short8 vb = *(const short8*)&uu.Evs[fd * 16 + l15][kb * 32 + quad * 8];
      ob[fd] = MFMA(pa, vb, ob[fd]);
    }
  }

  // final reductions
  #pragma unroll
  for (int st = 16; st < 64; st <<= 1){
    ll_mx += __shfl_xor(ll_mx, st, 64);
    rsb_s += __shfl_xor(rsb_s, st, 64);
  }

  float inv[4], tl[4], trr[4];
  #pragma unroll
  for (int r = 0; r < 4; ++r){
    float L   = __shfl(lacc[r], quad << 4);
    float l0  = __shfl(ll0v[r], quad << 4);
    int src   = (quad << 4) + rqb + r;
    float lmx = __shfl(ll_mx, src);
    float rv  = __shfl(rsb_s, src);
    inv[r] = 1.f / L;
    tl[r]  = (l0 + lmx) * inv[r];
    trr[r] = 1.f - tl[r] - rv * inv[r];
  }

  #pragma unroll
  for (int fd = 0; fd < 4; ++fd){
    int dim = fd * 16 + l15;
    float evL = embv[(size_t)128 * 64 + dim];   // ridx=128 (k <= q-64)
    float evR = embv[dim];                      // ridx=0   (k >= q+64)
    #pragma unroll
    for (int r = 0; r < 4; ++r){
      int row = q0 + wm + rqb + r;
      float val = (o[fd][r] + ob[fd][r]) * inv[r] + tl[r] * evL + trr[r] * evR;
      out[((size_t)(b * S_LEN + row)) * DMODEL + h * 64 + dim] = val;
    }
  }
}

extern "C" void kernel_launch(void* const* d_in, const int* in_sizes, int n_in,
                              void* d_out, int out_size, void* d_ws, size_t ws_size,
                              hipStream_t stream){
  const float* X    = (const float*)d_in[0];
  const float* mask = (const float*)d_in[1];
  const float* Wq   = (const float*)d_in[2];
  const float* bq   = (const float*)d_in[3];
  const float* Wk   = (const float*)d_in[4];
  const float* bk   = (const float*)d_in[5];
  const float* Wv   = (const float*)d_in[6];
  const float* bv   = (const float*)d_in[7];
  const float* embk = (const float*)d_in[8];
  const float* embv = (const float*)d_in[9];
  float* out = (float*)d_out;
  char* ws = (char*)d_ws;

  u16* XB   = (u16*)(ws + 0);            // 8,388,608
  u16* WT   = (u16*)(ws + 8388608);      // 6,291,456
  u16* EKB  = (u16*)(ws + 14680064);     // 18,432
  u16* QS   = (u16*)(ws + 14698496);     // 8,388,608
  u16* KB   = (u16*)(ws + 23087104);     // 8,388,608
  u16* VT   = (u16*)(ws + 39864320);     // 8,388,608 (VB slot at 31475712 now unused)
  float* MSL = (float*)(ws + 48252928);  // 16,384  (end 48,269,312)

  k_prep   <<<4916, 256, 0, stream>>>(X, Wq, Wk, Wv, embk, mask, XB, WT, EKB, MSL);
  k_qkv    <<<dim3(8, 32, 3), 256, 0, stream>>>(XB, WT, bq, bk, bv, QS, KB, VT);
  k_flash  <<<dim3(32, 32), 256, 0, stream>>>(QS, KB, VT, EKB, MSL, embv, out);
}

// Round 4
// 223.694 us; speedup vs baseline: 1.5753x; 1.5753x over previous
//
#include <hip/hip_runtime.h>
#include <stdint.h>

typedef unsigned short u16;
typedef __attribute__((ext_vector_type(8))) short short8;
typedef __attribute__((ext_vector_type(4))) float f32x4;
typedef __attribute__((ext_vector_type(4))) unsigned short u16x4;

#define S_LEN 2048
#define NH 16
#define DMODEL 1024
#define NR 129
#define LOG2E 1.44269504f

#define MFMA(a,b,c) __builtin_amdgcn_mfma_f32_16x16x32_bf16((a),(b),(c),0,0,0)

__device__ __forceinline__ u16 f2bf(float f){            // RTNE
  uint32_t u = __float_as_uint(f);
  u += 0x7fff + ((u >> 16) & 1);
  return (u16)(u >> 16);
}
__device__ __forceinline__ u16 f2bfa(float f){           // RTNA (cheap, p>=0)
  return (u16)((__float_as_uint(f) + 0x8000u) >> 16);
}
__device__ __forceinline__ float bf2f(u16 h){ return __uint_as_float(((uint32_t)h) << 16); }

__device__ __forceinline__ uint32_t cvtpk(float lo, float hi){
  uint32_t r;
  asm("v_cvt_pk_bf16_f32 %0, %1, %2" : "=v"(r) : "v"(lo), "v"(hi));
  return r;
}

// async global->LDS, 16B/lane; lds dest = wave-uniform base + lane*16 (HW)
__device__ __forceinline__ void gl_lds16(const u16* g, u16* l){
  __builtin_amdgcn_global_load_lds((const __attribute__((address_space(1))) void*)g,
                                   (__attribute__((address_space(3))) void*)l, 16, 0, 0);
}

// ---------------- prep ----------------
__global__ __launch_bounds__(256) void k_prep(const float* __restrict__ X,
                                              const float* __restrict__ Wq, const float* __restrict__ Wk,
                                              const float* __restrict__ Wv, const float* __restrict__ Wemb,
                                              const float* __restrict__ mask,
                                              u16* __restrict__ Xb, u16* __restrict__ Wt,
                                              u16* __restrict__ Eb, float* __restrict__ maskL){
  const int bid = blockIdx.x, tid = threadIdx.x;
  if (bid < 4096){
    int i = bid * 256 + tid;
    const float4* xp = (const float4*)X;
    float4 v = xp[i];
    u16x4 o; o.x = f2bf(v.x); o.y = f2bf(v.y); o.z = f2bf(v.z); o.w = f2bf(v.w);
    *(u16x4*)(Xb + (size_t)i * 4) = o;
  } else if (bid < 4864){
    int b2 = bid - 4096;
    int z = b2 >> 8;
    const float* W = (z == 0) ? Wq : (z == 1) ? Wk : Wv;
    u16* Ot = Wt + (size_t)z * 1024 * 1024;
    __shared__ float t[64][65];
    int k0 = ((b2 >> 4) & 15) * 64, n0 = (b2 & 15) * 64;
    int c = tid & 63, r0 = (tid >> 6) * 16;
    #pragma unroll
    for (int i = 0; i < 16; ++i) t[r0 + i][c] = W[(size_t)(k0 + r0 + i) * 1024 + n0 + c];
    __syncthreads();
    #pragma unroll
    for (int i = 0; i < 16; ++i) Ot[(size_t)(n0 + r0 + i) * 1024 + k0 + c] = f2bf(t[c][r0 + i]);
  } else if (bid < 4900){
    int idx = (bid - 4864) * 256 + tid;
    if (idx < 144 * 64){
      int r = idx >> 6;
      Eb[idx] = (r < NR) ? f2bf(Wemb[idx]) : (u16)0;
    }
  } else {
    int idx = (bid - 4900) * 256 + tid;
    maskL[idx] = mask[idx] * LOG2E;
  }
}

// ---------------- QKV GEMM (round-2 form, m97 structure) ----------------
__global__ __launch_bounds__(256) void k_qkv(const u16* __restrict__ Xb, const u16* __restrict__ Wt,
                                             const float* __restrict__ bq, const float* __restrict__ bk,
                                             const float* __restrict__ bv,
                                             u16* __restrict__ Qs, u16* __restrict__ Kb, u16* __restrict__ Vb){
  const int z = blockIdx.z;
  const u16* W = Wt + (size_t)z * 1024 * 1024;
  const float* bias = (z == 0) ? bq : (z == 1) ? bk : bv;
  u16* outp = (z == 0) ? Qs : (z == 1) ? Kb : Vb;
  const float vs = (z == 0) ? 0.125f * LOG2E : 1.0f;
  const int n0 = blockIdx.x * 128, m0 = blockIdx.y * 128;
  const int tid = threadIdx.x, w = tid >> 6, lane = tid & 63, l15 = lane & 15, quad = lane >> 4;
  const int wm = (w >> 1) * 64, wn = (w & 1) * 64;
  __shared__ __attribute__((aligned(16))) u16 As[128 * 32];
  __shared__ __attribute__((aligned(16))) u16 Bs[128 * 32];
  f32x4 acc[4][4];
  #pragma unroll
  for (int i = 0; i < 4; ++i)
    #pragma unroll
    for (int j = 0; j < 4; ++j) acc[i][j] = (f32x4){0.f,0.f,0.f,0.f};

  const int rA = lane >> 2, cA = (lane & 3) * 8;
  const u16* aBase = Xb + (size_t)(m0 + w * 16 + rA) * 1024 + cA;
  const u16* bBase = W  + (size_t)(n0 + w * 16 + rA) * 1024 + cA;
  u16* aDst0 = As + (w * 16) * 32;  u16* aDst1 = As + (64 + w * 16) * 32;
  u16* bDst0 = Bs + (w * 16) * 32;  u16* bDst1 = Bs + (64 + w * 16) * 32;

  for (int k0 = 0; k0 < 1024; k0 += 32){
    __syncthreads();
    gl_lds16(aBase + k0,             aDst0);
    gl_lds16(aBase + 64 * 1024 + k0, aDst1);
    gl_lds16(bBase + k0,             bDst0);
    gl_lds16(bBase + 64 * 1024 + k0, bDst1);
    __syncthreads();
    short8 af[4], bfr[4];
    #pragma unroll
    for (int f = 0; f < 4; ++f){
      af[f]  = *(const short8*)(As + (wm + f * 16 + l15) * 32 + quad * 8);
      bfr[f] = *(const short8*)(Bs + (wn + f * 16 + l15) * 32 + quad * 8);
    }
    #pragma unroll
    for (int i = 0; i < 4; ++i)
      #pragma unroll
      for (int j = 0; j < 4; ++j) acc[i][j] = MFMA(af[i], bfr[j], acc[i][j]);
  }
  #pragma unroll
  for (int i = 0; i < 4; ++i){
    #pragma unroll
    for (int j = 0; j < 4; ++j){
      int col = n0 + wn + j * 16 + l15;
      float bsv = bias[col];
      int hh = col >> 6, jd = col & 63;
      #pragma unroll
      for (int r = 0; r < 4; ++r){
        int row = m0 + wm + i * 16 + quad * 4 + r;
        int bb = row >> 11, s = row & 2047;
        float vv = (acc[i][j][r] + bsv) * vs;
        outp[(((size_t)(bb * 16 + hh)) * S_LEN + s) * 64 + jd] = f2bf(vv);
      }
    }
  }
}

// ---------------- transpose V with PV column-permute baked in ----------------
// Vp[g][d][s0 + perm(c)] = V[g][s0+c][d], perm(c) = ((c>>2)&3)*16 + (c>>4)*4 + (c&3)
__global__ __launch_bounds__(256) void k_transv(const u16* __restrict__ Vb, u16* __restrict__ Vp){
  const int g = blockIdx.y; const int s0 = blockIdx.x * 64;
  __shared__ __attribute__((aligned(16))) u16 t[64][72];
  const int tid = threadIdx.x;
  #pragma unroll
  for (int i = 0; i < 2; ++i){
    int c = tid + i * 256; int r = c >> 3, ch = (c & 7) * 8;
    *(short8*)&t[r][ch] = *(const short8*)(Vb + ((size_t)g * S_LEN + s0 + r) * 64 + ch);
  }
  __syncthreads();
  #pragma unroll
  for (int i = 0; i < 2; ++i){
    int c = tid + i * 256; int d = c >> 3, ch = (c & 7) * 8;
    int q = (ch >> 2) & 3, f = ch >> 4;
    u16x4 lo, hi;
    #pragma unroll
    for (int u = 0; u < 4; ++u){ lo[u] = t[ch + u][d]; hi[u] = t[ch + 4 + u][d]; }
    u16* base = Vp + ((size_t)g * 64 + d) * S_LEN + s0;
    *(u16x4*)(base + q * 16 + f * 4)       = lo;
    *(u16x4*)(base + (q + 1) * 16 + f * 4) = hi;
  }
}

// ---------------- fused flash + rel_v band ----------------
// Round 4: K/V staged via global_load_lds (async DMA, cooperative), double-buffered
// linear [64][64] tiles with two-sided XOR swizzle (granule ^= row&7): inverse-swizzled
// per-lane GLOBAL source + swizzled b128 reads. One barrier per tile; issue t+1's DMA
// at top of iteration t (full compute phase of latency cover). No ds_writes, no
// staging VGPRs. QEb 128-col (qeL redistributed via shfl); Psb XOR-swizzled [64][128].
// LDS = 65,536 B exactly -> 2 blocks/CU.
__global__ __launch_bounds__(256, 2) void k_flash(const u16* __restrict__ QS, const u16* __restrict__ KB,
                                                  const u16* __restrict__ VP, const u16* __restrict__ EMBK,
                                                  const float* __restrict__ maskL, const float* __restrict__ embv,
                                                  float* __restrict__ out){
  const int g = blockIdx.y; const int b = g >> 4; const int h = g & 15;
  const int q0 = blockIdx.x * 64;
  const int tid = threadIdx.x;
  const int w = tid >> 6; const int lane = tid & 63;
  const int l15 = lane & 15; const int quad = lane >> 4;
  const int wm = w * 16;
  const int rqb = quad * 4;
  const int qrow = q0 + wm + l15;

  __shared__ union UKE {
    struct {
      __attribute__((aligned(16))) u16 K[2][4096];   // [buf][row*64 + swz-granule*8+..]
      __attribute__((aligned(16))) u16 V[2][4096];
    } s;                                             // 32,768
    __attribute__((aligned(16))) u16 Evs[64][136];   // 17,408 (tail only)
  } uu;
  __shared__ __attribute__((aligned(16))) u16 QEb[4][16][128];  // 16,384
  __shared__ __attribute__((aligned(16))) u16 Psb[64][128];     // 16,384 (swizzled)

  // zero Psb
  {
    short8 z8 = (short8){0,0,0,0,0,0,0,0};
    for (int i = tid; i < 64 * 128 / 8; i += 256) ((short8*)Psb)[i] = z8;
  }

  // ---- staging geometry (per lane constants) ----
  const int lrow = lane >> 3;                      // 0..7
  const int lsw  = ((lane & 7) ^ lrow) * 8;        // inverse-swizzled source granule (u16)
  const u16* kS = KB + ((size_t)g * S_LEN + w * 16 + lrow) * 64 + lsw;        // + (kt+inst*8)*64
  const u16* vS = VP + ((size_t)(g * 64 + w * 16 + lrow)) * S_LEN + lsw;      // + kt + inst*8*S_LEN
  const float* mBase = maskL + b * S_LEN;

  // prologue: stage tile 0 into buf 0 (async)
  {
    u16* kd = uu.s.K[0] + (w * 16) * 64;
    u16* vd = uu.s.V[0] + (w * 16) * 64;
    gl_lds16(kS,               kd);
    gl_lds16(kS + 8 * 64,      kd + 512);
    gl_lds16(vS,               vd);
    gl_lds16(vS + 8 * S_LEN,   vd + 512);
  }

  f32x4 mcur[4];
  #pragma unroll
  for (int fn = 0; fn < 4; ++fn) mcur[fn] = *(const f32x4*)(mBase + fn * 16 + rqb);

  // Q fragments straight from global
  const u16* qptr = QS + ((size_t)g * S_LEN + q0 + wm + l15) * 64 + quad * 8;
  short8 qa0 = *(const short8*)qptr;
  short8 qa1 = *(const short8*)(qptr + 32);

  // qe = Q @ emb_k^T; cols 0..127 -> QEb; col 128 -> regs via shfl redistribution
  float qeLf = 0.f;
  #pragma unroll
  for (int fn = 0; fn < 9; ++fn){
    const u16* ep = EMBK + (fn * 16 + l15) * 64 + quad * 8;
    short8 eb0 = *(const short8*)ep;
    short8 eb1 = *(const short8*)(ep + 32);
    f32x4 c = (f32x4){0.f,0.f,0.f,0.f};
    c = MFMA(qa0, eb0, c);
    c = MFMA(qa1, eb1, c);
    if (fn < 8){
      #pragma unroll
      for (int r = 0; r < 4; ++r) QEb[w][rqb + r][fn * 16 + l15] = f2bf(c[r]);
    } else {
      // col 128 valid only in l15==0 lanes: qe[row=rqb+r][128] at lane quad*16, reg r.
      // This lane wants row = l15 -> source lane (l15>>2)*16, reg l15&3.
      int srcl = (l15 >> 2) << 4;
      float t0 = __shfl(c[0], srcl, 64);
      float t1 = __shfl(c[1], srcl, 64);
      float t2 = __shfl(c[2], srcl, 64);
      float t3 = __shfl(c[3], srcl, 64);
      int rr = l15 & 3;
      float qv = (rr == 0) ? t0 : (rr == 1) ? t1 : (rr == 2) ? t2 : t3;
      qeLf = bf2f(f2bf(qv));   // match round-2 bf16 quantization
    }
  }
  __syncthreads();   // drains vmcnt (tile-0 DMA) + lgkm (QEb/Psb) -> everything visible

  const float qeR = bf2f(QEb[w][l15][0]);
  const float qeL = qeLf;

  // ones-column B fragment for MFMA row-sums
  short8 bones;
  {
    short one = (l15 == 0) ? (short)0x3F80 : (short)0;
    #pragma unroll
    for (int j = 0; j < 8; ++j) bones[j] = one;
  }

  // swizzled read offsets (u16 units)
  const int rsw = l15 & 7;
  const int kO0 = ((quad     ^ rsw) * 8);
  const int kO1 = (((quad+4) ^ rsw) * 8);
  const int vO0 = (((quad*2)     ^ rsw) * 8);
  const int vO1 = (((quad*2 + 1) ^ rsw) * 8);

  f32x4 o[4];
  #pragma unroll
  for (int f = 0; f < 4; ++f) o[f] = (f32x4){0.f,0.f,0.f,0.f};
  f32x4 lacc = (f32x4){0.f,0.f,0.f,0.f};
  float ll0v[4] = {0.f,0.f,0.f,0.f};
  float ll_mx = 0.f;
  float rsb_s = 0.f;

  int cur = 0;
  for (int kt = 0; kt < S_LEN; kt += 64){
    const int ktn = kt + 64;

    // issue next-tile DMA into buf^1 (covered by this tile's full compute phase)
    if (ktn < S_LEN){
      u16* kd = uu.s.K[cur ^ 1] + (w * 16) * 64;
      u16* vd = uu.s.V[cur ^ 1] + (w * 16) * 64;
      gl_lds16(kS + (size_t)ktn * 64,        kd);
      gl_lds16(kS + (size_t)(ktn + 8) * 64,  kd + 512);
      gl_lds16(vS + ktn,                     vd);
      gl_lds16(vS + ktn + 8 * S_LEN,         vd + 512);
    }

    const bool leftC  = (kt <= q0 - 128);
    const bool rightC = (kt >= q0 + 128);
    const float qeadd = leftC ? qeL : (rightC ? qeR : 0.f);

    // QK^T from LDS K[cur]; C-init = mask(+qe)
    const u16* ks = uu.s.K[cur];
    f32x4 p4[4];
    __builtin_amdgcn_s_setprio(1);
    #pragma unroll
    for (int fn = 0; fn < 4; ++fn){
      const u16* krow = ks + (fn * 16 + l15) * 64;
      short8 kb0 = *(const short8*)(krow + kO0);
      short8 kb1 = *(const short8*)(krow + kO1);
      f32x4 c = mcur[fn] + qeadd;
      c = MFMA(kb0, qa0, c);
      c = MFMA(kb1, qa1, c);
      p4[fn] = c;
    }
    __builtin_amdgcn_s_setprio(0);

    // prefetch next mask into regs
    f32x4 mnext[4];
    if (ktn < S_LEN){
      #pragma unroll
      for (int fn = 0; fn < 4; ++fn) mnext[fn] = *(const f32x4*)(mBase + ktn + fn * 16 + rqb);
    }

    if (leftC | rightC){
      #pragma unroll
      for (int fn = 0; fn < 4; ++fn)
        #pragma unroll
        for (int r = 0; r < 4; ++r) p4[fn][r] = __builtin_amdgcn_exp2f(p4[fn][r]);
    } else {
      // mixed: per-element qe gather + band capture
      #pragma unroll
      for (int fn = 0; fn < 4; ++fn){
        int kbase = kt + fn * 16 + rqb;
        #pragma unroll
        for (int r = 0; r < 4; ++r){
          int dq = qrow - (kbase + r) + 64;
          int ridx = min(max(dq, 0), 127);
          float qv = (dq >= 128) ? qeL : bf2f(QEb[w][l15][ridx]);
          float p = __builtin_amdgcn_exp2f(p4[fn][r] + qv);
          ll_mx += (dq >= 128) ? p : 0.f;
          if (dq >= 1 && dq <= 127){
            int t = 127 - dq;
            Psb[wm + l15][(((t >> 3) ^ rsw) << 3) | (t & 7)] = f2bfa(p);
            rsb_s += p;
          }
          p4[fn][r] = p;
        }
      }
    }

    // pack P, MFMA row-sum, PV from V[cur]
    __builtin_amdgcn_s_setprio(1);
    const u16* vs = uu.s.V[cur];
    #pragma unroll
    for (int fp = 0; fp < 2; ++fp){
      union { uint32_t u[4]; short8 s8; } pk;
      pk.u[0] = cvtpk(p4[2 * fp][0],     p4[2 * fp][1]);
      pk.u[1] = cvtpk(p4[2 * fp][2],     p4[2 * fp][3]);
      pk.u[2] = cvtpk(p4[2 * fp + 1][0], p4[2 * fp + 1][1]);
      pk.u[3] = cvtpk(p4[2 * fp + 1][2], p4[2 * fp + 1][3]);
      short8 pa = pk.s8;
      lacc = MFMA(pa, bones, lacc);
      const int vO = fp ? vO1 : vO0;
      #pragma unroll
      for (int fd = 0; fd < 4; ++fd){
        short8 vb = *(const short8*)(vs + (fd * 16 + l15) * 64 + vO);
        o[fd] = MFMA(pa, vb, o[fd]);
      }
    }
    __builtin_amdgcn_s_setprio(0);

    if (kt == q0 - 128){
      #pragma unroll
      for (int r = 0; r < 4; ++r) ll0v[r] = lacc[r];
    }
    if (ktn < S_LEN){
      #pragma unroll
      for (int fn = 0; fn < 4; ++fn) mcur[fn] = mnext[fn];
    }
    __syncthreads();   // single barrier per tile (compiler drains vmcnt here)
    cur ^= 1;
  }

  // ---- band tail ----
  // build Evs over the dead K/V region: Evs[d][t] = emb_v[127-t][d] (t<=126), else 0
  {
    int d = tid & 63, t4 = tid >> 6;
    #pragma unroll
    for (int it = 0; it < 34; ++it){
      int t = t4 + it * 4;
      float v = (t <= 126) ? embv[(size_t)(127 - t) * 64 + d] : 0.f;
      uu.Evs[d][t] = f2bf(v);
    }
  }
  __syncthreads();

  f32x4 ob[4];
  #pragma unroll
  for (int f = 0; f < 4; ++f) ob[f] = (f32x4){0.f,0.f,0.f,0.f};
  #pragma unroll
  for (int kb = 0; kb < 4; ++kb){
    short8 pa = *(const short8*)&Psb[wm + l15][((kb * 4 + quad) ^ rsw) << 3];
    #pragma unroll
    for (int fd = 0; fd < 4; ++fd){
      short8 vb = *(const short8*)&uu.Evs[fd * 16 + l15][kb * 32 + quad * 8];
      ob[fd] = MFMA(pa, vb, ob[fd]);
    }
  }

  // final reductions
  #pragma unroll
  for (int st = 16; st < 64; st <<= 1){
    ll_mx += __shfl_xor(ll_mx, st, 64);
    rsb_s += __shfl_xor(rsb_s, st, 64);
  }

  float inv[4], tl[4], trr[4];
  #pragma unroll
  for (int r = 0; r < 4; ++r){
    float L   = __shfl(lacc[r], quad << 4);
    float l0  = __shfl(ll0v[r], quad << 4);
    int src   = (quad << 4) + rqb + r;
    float lmx = __shfl(ll_mx, src);
    float rv  = __shfl(rsb_s, src);
    inv[r] = 1.f / L;
    tl[r]  = (l0 + lmx) * inv[r];
    trr[r] = 1.f - tl[r] - rv * inv[r];
  }

  #pragma unroll
  for (int fd = 0; fd < 4; ++fd){
    int dim = fd * 16 + l15;
    float evL = embv[(size_t)128 * 64 + dim];
    float evR = embv[dim];
    #pragma unroll
    for (int r = 0; r < 4; ++r){
      int row = q0 + wm + rqb + r;
      float val = (o[fd][r] + ob[fd][r]) * inv[r] + tl[r] * evL + trr[r] * evR;
      out[((size_t)(b * S_LEN + row)) * DMODEL + h * 64 + dim] = val;
    }
  }
}

extern "C" void kernel_launch(void* const* d_in, const int* in_sizes, int n_in,
                              void* d_out, int out_size, void* d_ws, size_t ws_size,
                              hipStream_t stream){
  const float* X    = (const float*)d_in[0];
  const float* mask = (const float*)d_in[1];
  const float* Wq   = (const float*)d_in[2];
  const float* bq   = (const float*)d_in[3];
  const float* Wk   = (const float*)d_in[4];
  const float* bk   = (const float*)d_in[5];
  const float* Wv   = (const float*)d_in[6];
  const float* bv   = (const float*)d_in[7];
  const float* embk = (const float*)d_in[8];
  const float* embv = (const float*)d_in[9];
  float* out = (float*)d_out;
  char* ws = (char*)d_ws;

  u16* XB   = (u16*)(ws + 0);            // 8,388,608
  u16* WT   = (u16*)(ws + 8388608);      // 6,291,456
  u16* EKB  = (u16*)(ws + 14680064);     // 18,432
  u16* QS   = (u16*)(ws + 14698496);     // 8,388,608
  u16* KB   = (u16*)(ws + 23087104);     // 8,388,608
  u16* VB   = (u16*)(ws + 31475712);     // 8,388,608
  u16* VP   = (u16*)(ws + 39864320);     // 8,388,608 (column-permuted transposed V)
  float* MSL = (float*)(ws + 48252928);  // 16,384  (end 48,269,312)

  k_prep   <<<4916, 256, 0, stream>>>(X, Wq, Wk, Wv, embk, mask, XB, WT, EKB, MSL);
  k_qkv    <<<dim3(8, 32, 3), 256, 0, stream>>>(XB, WT, bq, bk, bv, QS, KB, VB);
  k_transv <<<dim3(32, 32), 256, 0, stream>>>(VB, VP);
  k_flash  <<<dim3(32, 32), 256, 0, stream>>>(QS, KB, VP, EKB, MSL, embv, out);
}